// Round 1
// baseline (424.866 us; speedup 1.0000x reference)
//
#include <hip/hip_runtime.h>
#include <stdint.h>

// MX fp8-e4m3 block quantize-dequantize, BLOCK=32 along last dim.
// Per block: amax -> bf16(amax/448) -> round-nearest at 8 mantissa bits (in bf16)
//            -> s (n/256, or 1.0 if 0)
// Per elem:  v = x/s; e = max(floor(log2|v|), -6); q = round_half_away(v*2^(3-e));
//            o = clip(q*2^(e-3), +-448); out = o*s   (f32 throughout, like jnp)

__device__ __forceinline__ float bf16_rne(float x) {
    // round-to-nearest-even f32 -> bf16 -> f32 (valid for all finite normals)
    uint32_t u = __float_as_uint(x);
    u = (u + 0x7fffu + ((u >> 16) & 1u)) & 0xffff0000u;
    return __uint_as_float(u);
}

__device__ __forceinline__ float quant_one(float x, float s) {
    float v  = x / s;                 // f32 / f32 (s exactly representable), IEEE div
    float av = fabsf(v);
    // floor(log2|v|) via exponent bits; subnormal/zero give e=-127 -> clamped to -6,
    // which matches the reference after its max(private_exp, -6) clamp.
    int e = (int)(__float_as_uint(av) >> 23) - 127;
    if (e < -6) e = -6;
    float q  = ldexpf(v, 3 - e);               // v / 2^e * 8   (exact)
    float rq = floorf(fabsf(q) + 0.5f);        // round half away from zero
    float o  = ldexpf(copysignf(rq, v), e - 3); // rq / 8 * 2^e (exact)
    o = fminf(fmaxf(o, -448.0f), 448.0f);      // saturate_normals
    o = (av <= 3.402823466e+38f) ? o : v;      // Inf/NaN passthrough (on v=xs)
    return o * s;
}

__global__ __launch_bounds__(256) void MXQuantizer_kernel(
        const float* __restrict__ in, float* __restrict__ out, long long n) {
    long long gid  = (long long)blockIdx.x * blockDim.x + threadIdx.x;
    long long base = gid * 8;
    if (base >= n) return;

    const float4* in4 = reinterpret_cast<const float4*>(in + base);
    float4 a = in4[0];
    float4 b = in4[1];

    // per-thread amax over 8 elems
    float m = fmaxf(fmaxf(fabsf(a.x), fabsf(a.y)), fmaxf(fabsf(a.z), fabsf(a.w)));
    m = fmaxf(m, fmaxf(fmaxf(fabsf(b.x), fabsf(b.y)), fmaxf(fabsf(b.z), fabsf(b.w))));
    // combine across the 4 lanes sharing one 32-element block
    m = fmaxf(m, __shfl_xor(m, 1, 64));
    m = fmaxf(m, __shfl_xor(m, 2, 64));

    // scale: bf16(amax/448), then round-nearest with 8 mantissa bits, in bf16 math
    float sb = bf16_rne(m / 448.0f);           // scales.astype(bf16)
    float t  = sb * 256.0f;                    // exact power-of-2 scaling
    float r  = floorf(bf16_rne(t + 0.5f));     // bf16 add + floor (t>=0 so sign=+)
    float s  = r * 0.00390625f;                // /256, exact
    if (s == 0.0f) s = 1.0f;                   // zero scales -> 1.0

    float v0 = quant_one(a.x, s);
    float v1 = quant_one(a.y, s);
    float v2 = quant_one(a.z, s);
    float v3 = quant_one(a.w, s);
    float v4 = quant_one(b.x, s);
    float v5 = quant_one(b.y, s);
    float v6 = quant_one(b.z, s);
    float v7 = quant_one(b.w, s);

    float4* out4 = reinterpret_cast<float4*>(out + base);
    out4[0] = make_float4(v0, v1, v2, v3);
    out4[1] = make_float4(v4, v5, v6, v7);
}

extern "C" void kernel_launch(void* const* d_in, const int* in_sizes, int n_in,
                              void* d_out, int out_size, void* d_ws, size_t ws_size,
                              hipStream_t stream) {
    const float* in = (const float*)d_in[0];
    float* out = (float*)d_out;
    long long n = (long long)in_sizes[0];          // 8192*8192, divisible by 2048
    long long threads = (n + 7) / 8;
    int block = 256;
    unsigned grid = (unsigned)((threads + block - 1) / block);
    MXQuantizer_kernel<<<grid, block, 0, stream>>>(in, out, n);
}

// Round 3
// 408.291 us; speedup vs baseline: 1.0406x; 1.0406x over previous
//
#include <hip/hip_runtime.h>
#include <stdint.h>

// MX fp8-e4m3 block quantize-dequantize, BLOCK=32 along last dim. Bit-exact
// vs the jax/numpy reference (absmax 0.0 in round 1).
//
// Layout: one wave (64 lanes) owns 512 contiguous elements, loaded as two
// perfectly coalesced 16B/lane chunks (1KB dense per wave load). 32-elem
// quant blocks == 8-lane groups; amax via 3 shfl_xor.
//
// NOTE: __builtin_nontemporal_* requires clang ext_vector_type, not the
// HIP_vector_type float4 (round-2 compile failure).

typedef float f32x4 __attribute__((ext_vector_type(4)));

__device__ __forceinline__ float bf16_rne(float x) {
    // round-to-nearest-even f32 -> bf16 -> f32 (finite inputs)
    uint32_t u = __float_as_uint(x);
    u = (u + 0x7fffu + ((u >> 16) & 1u)) & 0xffff0000u;
    return __uint_as_float(u);
}

__device__ __forceinline__ float block_scale(float m) {
    // scales = bf16(amax/448); nano-mantissa round at 8 bits (bf16 math);
    // zero -> 1.0
    float sb = bf16_rne(m / 448.0f);
    float t  = sb * 256.0f;                  // exact pow2 scaling
    float r  = floorf(bf16_rne(t + 0.5f));   // round half away (t >= 0)
    float s  = r * 0.00390625f;              // /256, exact
    return (s == 0.0f) ? 1.0f : s;
}

__device__ __forceinline__ float quant_one(float x, float s) {
    float v  = x / s;                        // IEEE f32 div (exactness matters)
    float av = fabsf(v);
    // floor(log2|v|) via exponent field; zero/denorm -> -127 -> clamped to -6,
    // matching the reference's max(private_exp, -6).
    int e = (int)(__float_as_uint(av) >> 23) - 127;
    if (e < -6) e = -6;
    float q  = ldexpf(v, 3 - e);                 // v / 2^e * 8   (exact)
    float rq = floorf(fabsf(q) + 0.5f);          // round half away from zero
    float o  = ldexpf(copysignf(rq, v), e - 3);  // rq / 8 * 2^e  (exact)
    o = fminf(fmaxf(o, -448.0f), 448.0f);        // saturate_normals
    o = (av <= 3.402823466e+38f) ? o : v;        // Inf/NaN passthrough
    return o * s;
}

__device__ __forceinline__ float amax4(f32x4 a) {
    return fmaxf(fmaxf(fabsf(a.x), fabsf(a.y)), fmaxf(fabsf(a.z), fabsf(a.w)));
}

__device__ __forceinline__ f32x4 quant4(f32x4 a, float s) {
    f32x4 r;
    r.x = quant_one(a.x, s);
    r.y = quant_one(a.y, s);
    r.z = quant_one(a.z, s);
    r.w = quant_one(a.w, s);
    return r;
}

__global__ __launch_bounds__(256) void MXQuantizer_kernel(
        const float* __restrict__ in, float* __restrict__ out, long long n) {
    long long tid  = (long long)blockIdx.x * blockDim.x + threadIdx.x;
    long long wave = tid >> 6;
    int lane = (int)(threadIdx.x & 63);
    long long base0 = wave * 512 + (long long)lane * 4;  // chunk 0
    long long base1 = base0 + 256;                       // chunk 1
    if (base0 >= n) return;  // n is a multiple of 512 (8192x8192)

    f32x4 a = __builtin_nontemporal_load(
        reinterpret_cast<const f32x4*>(in + base0));
    f32x4 b = __builtin_nontemporal_load(
        reinterpret_cast<const f32x4*>(in + base1));

    // per-block (32 elems = 8 lanes x 4) amax via butterfly over lane bits 0..2
    float m0 = amax4(a);
    float m1 = amax4(b);
    m0 = fmaxf(m0, __shfl_xor(m0, 1, 64));
    m1 = fmaxf(m1, __shfl_xor(m1, 1, 64));
    m0 = fmaxf(m0, __shfl_xor(m0, 2, 64));
    m1 = fmaxf(m1, __shfl_xor(m1, 2, 64));
    m0 = fmaxf(m0, __shfl_xor(m0, 4, 64));
    m1 = fmaxf(m1, __shfl_xor(m1, 4, 64));

    float s0 = block_scale(m0);
    float s1 = block_scale(m1);

    f32x4 o0 = quant4(a, s0);
    f32x4 o1 = quant4(b, s1);

    __builtin_nontemporal_store(o0, reinterpret_cast<f32x4*>(out + base0));
    __builtin_nontemporal_store(o1, reinterpret_cast<f32x4*>(out + base1));
}

extern "C" void kernel_launch(void* const* d_in, const int* in_sizes, int n_in,
                              void* d_out, int out_size, void* d_ws, size_t ws_size,
                              hipStream_t stream) {
    const float* in = (const float*)d_in[0];
    float* out = (float*)d_out;
    long long n = (long long)in_sizes[0];      // 8192*8192, multiple of 512
    long long threads = n / 8;                 // 8 elems per thread
    int block = 256;
    unsigned grid = (unsigned)((threads + block - 1) / block);
    MXQuantizer_kernel<<<grid, block, 0, stream>>>(in, out, n);
}